// Round 1
// baseline (519.699 us; speedup 1.0000x reference)
//
#include <hip/hip_runtime.h>
#include <cstdint>

#define HW 4096

typedef __attribute__((ext_vector_type(8))) short bf16x8;
typedef __attribute__((ext_vector_type(4))) float f32x4;

__device__ __forceinline__ short f2bf(float f) {
    union { float f; uint32_t u; } v; v.f = f;
    uint32_t u = v.u;
    uint32_t r = (u + 0x7FFFu + ((u >> 16) & 1u)) >> 16;
    return (short)(r & 0xFFFFu);
}

// ---------------------------------------------------------------------------
// Kernel 1: offset-predicting 3x3 conv (fp32 direct, LDS-tiled).
// Block = (tile 8x8 spatial, b). 4 waves, each owns 64 of the 256 cin.
// Barrier-free staging: wave w stages its own 10x10 halo in xs[w].
// ---------------------------------------------------------------------------
__global__ __launch_bounds__(256) void k_offconv(
    const float* __restrict__ x, const float* __restrict__ w_off,
    const float* __restrict__ b_off, float* __restrict__ om)
{
    __shared__ float xs[4][104];
    __shared__ float red[4][54][64];
    const int t = threadIdx.x;
    const int wv = t >> 6, lane = t & 63;
    const int tile = blockIdx.x, b = blockIdx.y;
    const int ty0 = (tile >> 3) << 3, tx0 = (tile & 7) << 3;
    const int sy = lane >> 3, sx = lane & 7;

    float acc[54];
#pragma unroll
    for (int i = 0; i < 54; ++i) acc[i] = 0.f;

    const float* xb = x + (size_t)b * 256 * HW;

    for (int it = 0; it < 64; ++it) {
        // force wave-uniform (SGPR) so weight loads become s_load
        const int cin = __builtin_amdgcn_readfirstlane(wv * 64 + it);
        const float* xp = xb + (size_t)cin * HW;
#pragma unroll
        for (int s = 0; s < 2; ++s) {
            int hidx = lane + s * 64;
            if (hidx < 100) {
                int hy = hidx / 10;
                int hx = hidx - hy * 10;
                int gy = ty0 + hy - 1, gx = tx0 + hx - 1;
                float v = 0.f;
                if (gy >= 0 && gy < 64 && gx >= 0 && gx < 64) v = xp[gy * 64 + gx];
                xs[wv][hidx] = v;
            }
        }
        float tv[9];
#pragma unroll
        for (int dy = 0; dy < 3; ++dy)
#pragma unroll
            for (int dx = 0; dx < 3; ++dx)
                tv[dy * 3 + dx] = xs[wv][(sy + dy) * 10 + (sx + dx)];

        const float* wr = w_off + cin * 9;
#pragma unroll
        for (int oc = 0; oc < 54; ++oc) {
            const float* wo = wr + oc * 2304;
#pragma unroll
            for (int tp = 0; tp < 9; ++tp)
                acc[oc] = fmaf(wo[tp], tv[tp], acc[oc]);
        }
    }
#pragma unroll
    for (int oc = 0; oc < 54; ++oc) red[wv][oc][lane] = acc[oc];
    __syncthreads();
    for (int j = 0; j < 14; ++j) {
        int el = t + j * 256;
        if (el < 3456) {
            int oc = el >> 6, sp = el & 63;
            float s = red[0][oc][sp] + red[1][oc][sp] + red[2][oc][sp] + red[3][oc][sp]
                    + b_off[oc];
            int spy = sp >> 3, spx = sp & 7;
            om[((size_t)b * 54 + oc) * HW + (ty0 + spy) * 64 + (tx0 + spx)] = s;
        }
    }
}

// ---------------------------------------------------------------------------
// Kernel 2: sampling plan. Per (b,dg,k,hw): 4 clamped indices + 4 bilinear
// weights with validity and sigmoid(mask) folded in.
// ---------------------------------------------------------------------------
__global__ __launch_bounds__(256) void k_plan(
    const float* __restrict__ om, float4* __restrict__ planw, int4* __restrict__ plani)
{
    int e = blockIdx.x * 256 + threadIdx.x;      // 294912 total
    int hw = e & 4095;
    int t2 = e >> 12;
    int k = t2 % 9;
    int t3 = t2 / 9;
    int dg = t3 & 1, b = t3 >> 1;
    int h = hw >> 6, w = hw & 63;
    int ky = k / 3, kx = k - ky * 3;
    const float* omb = om + (size_t)b * 54 * HW;
    float dy = omb[(dg * 18 + k) * HW + hw];
    float dx = omb[(dg * 18 + 9 + k) * HW + hw];
    float ms = omb[(36 + dg * 9 + k) * HW + hw];
    ms = 1.f / (1.f + __expf(-ms));
    float py = dy + (float)(h + ky - 1);
    float px = dx + (float)(w + kx - 1);
    float y0f = floorf(py), x0f = floorf(px);
    float wy1 = py - y0f, wx1 = px - x0f;
    float wy0 = 1.f - wy1, wx0 = 1.f - wx1;
    int y0 = (int)y0f, x0 = (int)x0f;
    int y1 = y0 + 1, x1 = x0 + 1;
    bool vy0 = (y0 >= 0 && y0 < 64), vy1 = (y1 >= 0 && y1 < 64);
    bool vx0 = (x0 >= 0 && x0 < 64), vx1 = (x1 >= 0 && x1 < 64);
    int cy0 = min(max(y0, 0), 63), cy1 = min(max(y1, 0), 63);
    int cx0 = min(max(x0, 0), 63), cx1 = min(max(x1, 0), 63);
    float4 wv;
    wv.x = (vy0 && vx0) ? wy0 * wx0 * ms : 0.f;
    wv.y = (vy0 && vx1) ? wy0 * wx1 * ms : 0.f;
    wv.z = (vy1 && vx0) ? wy1 * wx0 * ms : 0.f;
    wv.w = (vy1 && vx1) ? wy1 * wx1 * ms : 0.f;
    int4 iv = make_int4(cy0 * 64 + cx0, cy0 * 64 + cx1, cy1 * 64 + cx0, cy1 * 64 + cx1);
    planw[e] = wv;
    plani[e] = iv;
}

// ---------------------------------------------------------------------------
// Kernel 3: weight fp32 -> bf16 (K layout r = cin*9+k is weight's natural flat)
// ---------------------------------------------------------------------------
__global__ __launch_bounds__(256) void k_wcvt(
    const float4* __restrict__ w, short4* __restrict__ o)
{
    int i = blockIdx.x * 256 + threadIdx.x;      // 147456
    float4 v = w[i];
    o[i] = make_short4(f2bf(v.x), f2bf(v.y), f2bf(v.z), f2bf(v.w));
}

// ---------------------------------------------------------------------------
// Kernel 4: build colT[n][r] bf16, n = b*4096+hw (16384 rows), r = cin*9+k
// (2304, K-contiguous for the B^T-style GEMM). Gathers lane=hw coalesced;
// global writes coalesced via LDS transpose tile (row stride 146 bf16 = 73
// words, gcd(73,32)=1 -> conflict-free).
// Block = (hw row tile of 64, dg, b); threads = 4 csub x 64 hw.
// ---------------------------------------------------------------------------
__global__ __launch_bounds__(256) void k_col(
    const float* __restrict__ x, const float4* __restrict__ planw,
    const int4* __restrict__ plani, short* __restrict__ colT)
{
    __shared__ float sdw[4][9][64];
    __shared__ int   sdi[4][9][64];
    __shared__ short tb[64 * 146];
    const int t = threadIdx.x;
    const int csub = __builtin_amdgcn_readfirstlane(t >> 6);
    const int hl = t & 63;
    const int hwt = blockIdx.x, dg = blockIdx.y, b = blockIdx.z;

    for (int j = 0; j < 3; ++j) {
        int el = t + j * 256;
        if (el < 576) {
            int k = el >> 6, q = el & 63;
            int ge = ((b * 2 + dg) * 9 + k) * HW + hwt * 64 + q;
            float4 w4 = planw[ge];
            int4 i4 = plani[ge];
            sdw[0][k][q] = w4.x; sdw[1][k][q] = w4.y; sdw[2][k][q] = w4.z; sdw[3][k][q] = w4.w;
            sdi[0][k][q] = i4.x; sdi[1][k][q] = i4.y; sdi[2][k][q] = i4.z; sdi[3][k][q] = i4.w;
        }
    }
    __syncthreads();

    const float* xg = x + (size_t)(b * 256 + dg * 128) * HW;
    const int nrow = b * 4096 + hwt * 64;

    for (int cc = 0; cc < 8; ++cc) {
#pragma unroll
        for (int k = 0; k < 9; ++k) {
            float w0 = sdw[0][k][hl], w1 = sdw[1][k][hl], w2 = sdw[2][k][hl], w3 = sdw[3][k][hl];
            int i0 = sdi[0][k][hl], i1 = sdi[1][k][hl], i2 = sdi[2][k][hl], i3 = sdi[3][k][hl];
#pragma unroll
            for (int ci = 0; ci < 4; ++ci) {
                int cic = ci * 4 + csub;
                const float* pl = xg + (size_t)(cc * 16 + cic) * HW;
                float v = w0 * pl[i0] + w1 * pl[i1] + w2 * pl[i2] + w3 * pl[i3];
                tb[hl * 146 + cic * 9 + k] = f2bf(v);
            }
        }
        __syncthreads();
#pragma unroll
        for (int j = 0; j < 18; ++j) {
            int fl = t + j * 256;                 // 4608 uint writes
            int nw = fl / 72, rp = fl - nw * 72;
            uint32_t v = *(const uint32_t*)&tb[nw * 146 + rp * 2];
            size_t n = (size_t)(nrow + nw);
            *(uint32_t*)&colT[n * 2304 + dg * 1152 + cc * 144 + rp * 2] = v;
        }
        __syncthreads();
    }
}

// ---------------------------------------------------------------------------
// Kernel 5: bf16 GEMM  out[m,n] = sum_r A[m,r]*colT[n,r], M=256 N=16384 K=2304
// 128x128x32 tile, 4 waves (2x2), 4x4 16x16x32 MFMA per wave, reg prefetch.
// ---------------------------------------------------------------------------
__global__ __launch_bounds__(256) void k_gemm(
    const short* __restrict__ A, const short* __restrict__ Bm,
    const float* __restrict__ bias, float* __restrict__ out)
{
    __shared__ short As[128 * 32];
    __shared__ short Bs[128 * 32];
    const int t = threadIdx.x;
    const int wid = t >> 6, lane = t & 63;
    const int quad = lane >> 4, l16 = lane & 15;
    const int wm = wid >> 1, wn = wid & 1;
    const int bn = blockIdx.x, bm = blockIdx.y;
    const short* Ab = A + (size_t)(bm * 128) * 2304;
    const short* Bb = Bm + (size_t)(bn * 128) * 2304;
    const int r0 = t >> 2;
    const int ko = (t & 3) * 8;

    f32x4 acc[4][4];
#pragma unroll
    for (int i = 0; i < 4; ++i)
#pragma unroll
        for (int j = 0; j < 4; ++j) acc[i][j] = (f32x4){0.f, 0.f, 0.f, 0.f};

    uint4 a0 = *(const uint4*)(Ab + (size_t)r0 * 2304 + ko);
    uint4 a1 = *(const uint4*)(Ab + (size_t)(r0 + 64) * 2304 + ko);
    uint4 b0 = *(const uint4*)(Bb + (size_t)r0 * 2304 + ko);
    uint4 b1 = *(const uint4*)(Bb + (size_t)(r0 + 64) * 2304 + ko);

    for (int kc = 0; kc < 72; ++kc) {
        if (kc) __syncthreads();
        *(uint4*)&As[t * 8] = a0;
        *(uint4*)&As[2048 + t * 8] = a1;
        *(uint4*)&Bs[t * 8] = b0;
        *(uint4*)&Bs[2048 + t * 8] = b1;
        __syncthreads();
        if (kc < 71) {
            int k1 = (kc + 1) * 32 + ko;
            a0 = *(const uint4*)(Ab + (size_t)r0 * 2304 + k1);
            a1 = *(const uint4*)(Ab + (size_t)(r0 + 64) * 2304 + k1);
            b0 = *(const uint4*)(Bb + (size_t)r0 * 2304 + k1);
            b1 = *(const uint4*)(Bb + (size_t)(r0 + 64) * 2304 + k1);
        }
        bf16x8 af[4], bfr[4];
#pragma unroll
        for (int mi = 0; mi < 4; ++mi)
            af[mi] = *(const bf16x8*)&As[(wm * 64 + mi * 16 + l16) * 32 + quad * 8];
#pragma unroll
        for (int ni = 0; ni < 4; ++ni)
            bfr[ni] = *(const bf16x8*)&Bs[(wn * 64 + ni * 16 + l16) * 32 + quad * 8];
#pragma unroll
        for (int mi = 0; mi < 4; ++mi)
#pragma unroll
            for (int ni = 0; ni < 4; ++ni)
                acc[mi][ni] = __builtin_amdgcn_mfma_f32_16x16x32_bf16(
                    af[mi], bfr[ni], acc[mi][ni], 0, 0, 0);
    }

    const int m0 = bm * 128 + wm * 64;
    const int n0 = bn * 128 + wn * 64;
#pragma unroll
    for (int mi = 0; mi < 4; ++mi)
#pragma unroll
        for (int ni = 0; ni < 4; ++ni) {
            int n = n0 + ni * 16 + l16;
            int bidx = n >> 12, hw = n & 4095;
            float* op = out + (size_t)bidx * 256 * 4096 + hw;
#pragma unroll
            for (int i = 0; i < 4; ++i) {
                int m = m0 + mi * 16 + quad * 4 + i;
                op[(size_t)m * 4096] = acc[mi][ni][i] + bias[m];
            }
        }
}

// ---------------------------------------------------------------------------
extern "C" void kernel_launch(void* const* d_in, const int* in_sizes, int n_in,
                              void* d_out, int out_size, void* d_ws, size_t ws_size,
                              hipStream_t stream)
{
    const float* x      = (const float*)d_in[0];
    const float* w_off  = (const float*)d_in[1];
    const float* b_off  = (const float*)d_in[2];
    const float* weight = (const float*)d_in[3];
    const float* bias   = (const float*)d_in[4];
    float* out = (float*)d_out;
    char* ws = (char*)d_ws;

    float*  om    = (float*) (ws);                 // 4*54*4096*4      = 3,538,944 B
    float4* planw = (float4*)(ws + 3538944);       // 294912*16        = 4,718,592 B
    int4*   plani = (int4*)  (ws + 8257536);       // 294912*16        = 4,718,592 B
    short*  Wbf   = (short*) (ws + 12976128);      // 589824*2         = 1,179,648 B
    short*  colT  = (short*) (ws + 14155776);      // 16384*2304*2     = 75,497,472 B
                                                   // total ~85.5 MB of ws

    hipLaunchKernelGGL(k_offconv, dim3(64, 4), dim3(256), 0, stream, x, w_off, b_off, om);
    hipLaunchKernelGGL(k_plan, dim3(1152), dim3(256), 0, stream, om, planw, plani);
    hipLaunchKernelGGL(k_wcvt, dim3(576), dim3(256), 0, stream,
                       (const float4*)weight, (short4*)Wbf);
    hipLaunchKernelGGL(k_col, dim3(64, 2, 4), dim3(256), 0, stream, x, planw, plani, colT);
    hipLaunchKernelGGL(k_gemm, dim3(128, 2), dim3(256), 0, stream, Wbf, colT, bias, out);
}

// Round 2
// 390.885 us; speedup vs baseline: 1.3295x; 1.3295x over previous
//
#include <hip/hip_runtime.h>
#include <cstdint>

#define HW 4096

typedef __attribute__((ext_vector_type(8))) short bf16x8;
typedef __attribute__((ext_vector_type(4))) float f32x4;

__device__ __forceinline__ short f2bf(float f) {
    union { float f; uint32_t u; } v; v.f = f;
    uint32_t u = v.u;
    uint32_t r = (u + 0x7FFFu + ((u >> 16) & 1u)) >> 16;
    return (short)(r & 0xFFFFu);
}

// ---------------------------------------------------------------------------
// Kernel 0: repack offset-conv weights w_off[oc][cin][tap] -> wT[cin][512]
// (oc*9+tap contiguous, 64B-aligned rows) so the conv's wave-uniform weight
// reads become one sequential s_load stream per cin.
// ---------------------------------------------------------------------------
__global__ __launch_bounds__(256) void k_wt(
    const float* __restrict__ w_off, float* __restrict__ wT)
{
    int e = blockIdx.x * 256 + threadIdx.x;      // 486 blocks * 256 = 124416
    int cin = e / 486, j = e - cin * 486;
    int oc = j / 9, tap = j - oc * 9;
    wT[cin * 512 + j] = w_off[(oc * 256 + cin) * 9 + tap];
}

// ---------------------------------------------------------------------------
// Kernel 1: offset-predicting 3x3 conv (fp32 direct, LDS-tiled).
// Grid (tile, cs, b): 1024 blocks -> 4 blocks/CU (4 waves/SIMD) to hide the
// scalar-load latency of the weight stream. Each wave owns 16 cin; block
// reduces its 4 waves via LDS atomics and writes one partial; k_plan sums
// the 4 cs-partials.
// ---------------------------------------------------------------------------
__global__ __launch_bounds__(256, 4) void k_offconv(
    const float* __restrict__ x, const float* __restrict__ wT,
    float* __restrict__ om_p)     // [cs=4][B=4][54][HW]
{
    __shared__ float xs[4][104];
    __shared__ float red[3456];   // [54][64]
    const int t = threadIdx.x;
    const int wv = t >> 6, lane = t & 63;
    const int tile = blockIdx.x, cs = blockIdx.y, b = blockIdx.z;
    const int ty0 = (tile >> 3) << 3, tx0 = (tile & 7) << 3;
    const int sy = lane >> 3, sx = lane & 7;

    float acc[54];
#pragma unroll
    for (int i = 0; i < 54; ++i) acc[i] = 0.f;

    const float* xb = x + (size_t)b * 256 * HW;
    const int cin0 = cs * 64 + wv * 16;

    for (int it = 0; it < 16; ++it) {
        const int cin = __builtin_amdgcn_readfirstlane(cin0 + it);
        const float* xp = xb + (size_t)cin * HW;
#pragma unroll
        for (int s = 0; s < 2; ++s) {
            int hidx = lane + s * 64;
            if (hidx < 100) {
                int hy = hidx / 10;
                int hx = hidx - hy * 10;
                int gy = ty0 + hy - 1, gx = tx0 + hx - 1;
                float v = 0.f;
                if (gy >= 0 && gy < 64 && gx >= 0 && gx < 64) v = xp[gy * 64 + gx];
                xs[wv][hidx] = v;
            }
        }
        float tv[9];
#pragma unroll
        for (int dy = 0; dy < 3; ++dy)
#pragma unroll
            for (int dx = 0; dx < 3; ++dx)
                tv[dy * 3 + dx] = xs[wv][(sy + dy) * 10 + (sx + dx)];

        const float* wr = wT + (size_t)cin * 512;   // 486 sequential dwords
#pragma unroll
        for (int oc = 0; oc < 54; ++oc) {
#pragma unroll
            for (int tp = 0; tp < 9; ++tp)
                acc[oc] = fmaf(wr[oc * 9 + tp], tv[tp], acc[oc]);
        }
    }

    // zero the reduction buffer
#pragma unroll
    for (int j = 0; j < 14; ++j) {
        int el = t + j * 256;
        if (el < 3456) red[el] = 0.f;
    }
    __syncthreads();
#pragma unroll
    for (int oc = 0; oc < 54; ++oc)
        atomicAdd(&red[oc * 64 + lane], acc[oc]);
    __syncthreads();
    for (int j = 0; j < 14; ++j) {
        int el = t + j * 256;
        if (el < 3456) {
            int oc = el >> 6, sp = el & 63;
            int spy = sp >> 3, spx = sp & 7;
            om_p[(size_t)((cs * 4 + b) * 54 + oc) * HW + (ty0 + spy) * 64 + (tx0 + spx)]
                = red[el];
        }
    }
}

// ---------------------------------------------------------------------------
// Kernel 2: sampling plan. Sums the 4 cs-partials of om, adds b_off, then
// per (b,dg,k,hw): 4 clamped indices + 4 bilinear weights with validity and
// sigmoid(mask) folded in.
// ---------------------------------------------------------------------------
__global__ __launch_bounds__(256) void k_plan(
    const float* __restrict__ om_p, const float* __restrict__ b_off,
    float4* __restrict__ planw, int4* __restrict__ plani)
{
    const int CSS = 4 * 54 * HW;                 // cs stride in floats
    int e = blockIdx.x * 256 + threadIdx.x;      // 294912 total
    int hw = e & 4095;
    int t2 = e >> 12;
    int k = t2 % 9;
    int t3 = t2 / 9;
    int dg = t3 & 1, b = t3 >> 1;
    int h = hw >> 6, w = hw & 63;
    int ky = k / 3, kx = k - ky * 3;
    int cdy = dg * 18 + k, cdx = dg * 18 + 9 + k, cms = 36 + dg * 9 + k;
    size_t base = (size_t)b * 54 * HW + hw;
    float dy = b_off[cdy], dx = b_off[cdx], ms = b_off[cms];
#pragma unroll
    for (int cs = 0; cs < 4; ++cs) {
        const float* p = om_p + (size_t)cs * CSS + base;
        dy += p[(size_t)cdy * HW];
        dx += p[(size_t)cdx * HW];
        ms += p[(size_t)cms * HW];
    }
    ms = 1.f / (1.f + __expf(-ms));
    float py = dy + (float)(h + ky - 1);
    float px = dx + (float)(w + kx - 1);
    float y0f = floorf(py), x0f = floorf(px);
    float wy1 = py - y0f, wx1 = px - x0f;
    float wy0 = 1.f - wy1, wx0 = 1.f - wx1;
    int y0 = (int)y0f, x0 = (int)x0f;
    int y1 = y0 + 1, x1 = x0 + 1;
    bool vy0 = (y0 >= 0 && y0 < 64), vy1 = (y1 >= 0 && y1 < 64);
    bool vx0 = (x0 >= 0 && x0 < 64), vx1 = (x1 >= 0 && x1 < 64);
    int cy0 = min(max(y0, 0), 63), cy1 = min(max(y1, 0), 63);
    int cx0 = min(max(x0, 0), 63), cx1 = min(max(x1, 0), 63);
    float4 wv;
    wv.x = (vy0 && vx0) ? wy0 * wx0 * ms : 0.f;
    wv.y = (vy0 && vx1) ? wy0 * wx1 * ms : 0.f;
    wv.z = (vy1 && vx0) ? wy1 * wx0 * ms : 0.f;
    wv.w = (vy1 && vx1) ? wy1 * wx1 * ms : 0.f;
    int4 iv = make_int4(cy0 * 64 + cx0, cy0 * 64 + cx1, cy1 * 64 + cx0, cy1 * 64 + cx1);
    planw[e] = wv;
    plani[e] = iv;
}

// ---------------------------------------------------------------------------
// Kernel 3: weight fp32 -> bf16 (K layout r = cin*9+k is weight's natural flat)
// ---------------------------------------------------------------------------
__global__ __launch_bounds__(256) void k_wcvt(
    const float4* __restrict__ w, short4* __restrict__ o)
{
    int i = blockIdx.x * 256 + threadIdx.x;      // 147456
    float4 v = w[i];
    o[i] = make_short4(f2bf(v.x), f2bf(v.y), f2bf(v.z), f2bf(v.w));
}

// ---------------------------------------------------------------------------
// Kernel 4: build colT[n][r] bf16, n = b*4096+hw (16384 rows), r = cin*9+k
// (2304, K-contiguous for the B^T-style GEMM). Gathers lane=hw coalesced;
// global writes coalesced via LDS transpose tile (row stride 146 bf16 = 73
// words, gcd(73,32)=1 -> conflict-free).
// Block = (hw row tile of 64, dg, b); threads = 4 csub x 64 hw.
// ---------------------------------------------------------------------------
__global__ __launch_bounds__(256) void k_col(
    const float* __restrict__ x, const float4* __restrict__ planw,
    const int4* __restrict__ plani, short* __restrict__ colT)
{
    __shared__ float sdw[4][9][64];
    __shared__ int   sdi[4][9][64];
    __shared__ short tb[64 * 146];
    const int t = threadIdx.x;
    const int csub = __builtin_amdgcn_readfirstlane(t >> 6);
    const int hl = t & 63;
    const int hwt = blockIdx.x, dg = blockIdx.y, b = blockIdx.z;

    for (int j = 0; j < 3; ++j) {
        int el = t + j * 256;
        if (el < 576) {
            int k = el >> 6, q = el & 63;
            int ge = ((b * 2 + dg) * 9 + k) * HW + hwt * 64 + q;
            float4 w4 = planw[ge];
            int4 i4 = plani[ge];
            sdw[0][k][q] = w4.x; sdw[1][k][q] = w4.y; sdw[2][k][q] = w4.z; sdw[3][k][q] = w4.w;
            sdi[0][k][q] = i4.x; sdi[1][k][q] = i4.y; sdi[2][k][q] = i4.z; sdi[3][k][q] = i4.w;
        }
    }
    __syncthreads();

    const float* xg = x + (size_t)(b * 256 + dg * 128) * HW;
    const int nrow = b * 4096 + hwt * 64;

    for (int cc = 0; cc < 8; ++cc) {
#pragma unroll
        for (int k = 0; k < 9; ++k) {
            float w0 = sdw[0][k][hl], w1 = sdw[1][k][hl], w2 = sdw[2][k][hl], w3 = sdw[3][k][hl];
            int i0 = sdi[0][k][hl], i1 = sdi[1][k][hl], i2 = sdi[2][k][hl], i3 = sdi[3][k][hl];
#pragma unroll
            for (int ci = 0; ci < 4; ++ci) {
                int cic = ci * 4 + csub;
                const float* pl = xg + (size_t)(cc * 16 + cic) * HW;
                float v = w0 * pl[i0] + w1 * pl[i1] + w2 * pl[i2] + w3 * pl[i3];
                tb[hl * 146 + cic * 9 + k] = f2bf(v);
            }
        }
        __syncthreads();
#pragma unroll
        for (int j = 0; j < 18; ++j) {
            int fl = t + j * 256;                 // 4608 uint writes
            int nw = fl / 72, rp = fl - nw * 72;
            uint32_t v = *(const uint32_t*)&tb[nw * 146 + rp * 2];
            size_t n = (size_t)(nrow + nw);
            *(uint32_t*)&colT[n * 2304 + dg * 1152 + cc * 144 + rp * 2] = v;
        }
        __syncthreads();
    }
}

// ---------------------------------------------------------------------------
// Kernel 5: bf16 GEMM  out[m,n] = sum_r A[m,r]*colT[n,r], M=256 N=16384 K=2304
// 64x128x32 tile -> grid (128,4) = 512 blocks = 2 blocks/CU (was 1).
// 4 waves (2x2), each wave 32x64 = 2x4 16x16x32 MFMA tiles, reg prefetch.
// ---------------------------------------------------------------------------
__global__ __launch_bounds__(256) void k_gemm(
    const short* __restrict__ A, const short* __restrict__ Bm,
    const float* __restrict__ bias, float* __restrict__ out)
{
    __shared__ short As[64 * 32];
    __shared__ short Bs[128 * 32];
    const int t = threadIdx.x;
    const int wid = t >> 6, lane = t & 63;
    const int quad = lane >> 4, l16 = lane & 15;
    const int wm = wid >> 1, wn = wid & 1;
    const int bn = blockIdx.x, bm = blockIdx.y;
    const short* Ab = A + (size_t)(bm * 64) * 2304;
    const short* Bb = Bm + (size_t)(bn * 128) * 2304;
    const int ra = t >> 2;            // A row 0..63
    const int ko = (t & 3) * 8;       // k offset in shorts

    f32x4 acc[2][4];
#pragma unroll
    for (int i = 0; i < 2; ++i)
#pragma unroll
        for (int j = 0; j < 4; ++j) acc[i][j] = (f32x4){0.f, 0.f, 0.f, 0.f};

    uint4 a0 = *(const uint4*)(Ab + (size_t)ra * 2304 + ko);
    uint4 b0 = *(const uint4*)(Bb + (size_t)ra * 2304 + ko);
    uint4 b1 = *(const uint4*)(Bb + (size_t)(ra + 64) * 2304 + ko);

    for (int kc = 0; kc < 72; ++kc) {
        if (kc) __syncthreads();
        *(uint4*)&As[t * 8] = a0;
        *(uint4*)&Bs[t * 8] = b0;
        *(uint4*)&Bs[2048 + t * 8] = b1;
        __syncthreads();
        if (kc < 71) {
            int k1 = (kc + 1) * 32 + ko;
            a0 = *(const uint4*)(Ab + (size_t)ra * 2304 + k1);
            b0 = *(const uint4*)(Bb + (size_t)ra * 2304 + k1);
            b1 = *(const uint4*)(Bb + (size_t)(ra + 64) * 2304 + k1);
        }
        bf16x8 af[2], bfr[4];
#pragma unroll
        for (int mi = 0; mi < 2; ++mi)
            af[mi] = *(const bf16x8*)&As[(wm * 32 + mi * 16 + l16) * 32 + quad * 8];
#pragma unroll
        for (int ni = 0; ni < 4; ++ni)
            bfr[ni] = *(const bf16x8*)&Bs[(wn * 64 + ni * 16 + l16) * 32 + quad * 8];
#pragma unroll
        for (int mi = 0; mi < 2; ++mi)
#pragma unroll
            for (int ni = 0; ni < 4; ++ni)
                acc[mi][ni] = __builtin_amdgcn_mfma_f32_16x16x32_bf16(
                    af[mi], bfr[ni], acc[mi][ni], 0, 0, 0);
    }

    const int m0 = bm * 64 + wm * 32;
    const int n0 = bn * 128 + wn * 64;
#pragma unroll
    for (int mi = 0; mi < 2; ++mi)
#pragma unroll
        for (int ni = 0; ni < 4; ++ni) {
            int n = n0 + ni * 16 + l16;
            int bidx = n >> 12, hw = n & 4095;
            float* op = out + (size_t)bidx * 256 * 4096 + hw;
#pragma unroll
            for (int i = 0; i < 4; ++i) {
                int m = m0 + mi * 16 + quad * 4 + i;
                op[(size_t)m * 4096] = acc[mi][ni][i] + bias[m];
            }
        }
}

// ---------------------------------------------------------------------------
extern "C" void kernel_launch(void* const* d_in, const int* in_sizes, int n_in,
                              void* d_out, int out_size, void* d_ws, size_t ws_size,
                              hipStream_t stream)
{
    const float* x      = (const float*)d_in[0];
    const float* w_off  = (const float*)d_in[1];
    const float* b_off  = (const float*)d_in[2];
    const float* weight = (const float*)d_in[3];
    const float* bias   = (const float*)d_in[4];
    float* out = (float*)d_out;
    char* ws = (char*)d_ws;

    // ws layout (om_p aliases the head of colT: om_p is fully consumed by
    // k_plan before k_col writes colT — stream-ordered):
    float4* planw = (float4*)(ws);                 // 4,718,592 B
    int4*   plani = (int4*)  (ws + 4718592);       // 4,718,592 B
    short*  Wbf   = (short*) (ws + 9437184);       // 1,179,648 B
    float*  wT    = (float*) (ws + 10616832);      //   524,288 B
    short*  colT  = (short*) (ws + 11141120);      // 75,497,472 B  (ends 86,638,592)
    float*  om_p  = (float*) (ws + 11141120);      // 14,155,776 B (alias, dead before k_col)

    hipLaunchKernelGGL(k_wt, dim3(486), dim3(256), 0, stream, w_off, wT);
    hipLaunchKernelGGL(k_offconv, dim3(64, 4, 4), dim3(256), 0, stream, x, wT, om_p);
    hipLaunchKernelGGL(k_plan, dim3(1152), dim3(256), 0, stream, om_p, b_off, planw, plani);
    hipLaunchKernelGGL(k_wcvt, dim3(576), dim3(256), 0, stream,
                       (const float4*)weight, (short4*)Wbf);
    hipLaunchKernelGGL(k_col, dim3(64, 2, 4), dim3(256), 0, stream, x, planw, plani, colT);
    hipLaunchKernelGGL(k_gemm, dim3(128, 4), dim3(256), 0, stream, Wbf, colT, bias, out);
}

// Round 3
// 237.919 us; speedup vs baseline: 2.1844x; 1.6429x over previous
//
#include <hip/hip_runtime.h>
#include <cstdint>

#define HW 4096

typedef __attribute__((ext_vector_type(8))) short bf16x8;
typedef __attribute__((ext_vector_type(4))) float f32x4;

__device__ __forceinline__ short f2bf(float f) {
    union { float f; uint32_t u; } v; v.f = f;
    uint32_t u = v.u;
    uint32_t r = (u + 0x7FFFu + ((u >> 16) & 1u)) >> 16;
    return (short)(r & 0xFFFFu);
}
__device__ __forceinline__ float bf2f(unsigned short u) {
    union { uint32_t i; float f; } v; v.i = (uint32_t)u << 16; return v.f;
}
// async global->LDS, 16B per lane; LDS dest must be wavebase + lane*16
__device__ __forceinline__ void glds16(const void* g, void* l) {
    __builtin_amdgcn_global_load_lds(
        (const __attribute__((address_space(1))) void*)g,
        (__attribute__((address_space(3))) void*)l, 16, 0, 0);
}

// ---------------------------------------------------------------------------
// Kernel 1: transpose x[b][c][hw] (fp32) -> xT[b][hw][c] (bf16).
// 64c x 64hw tiles via LDS.
// ---------------------------------------------------------------------------
__global__ __launch_bounds__(256) void k_xt(
    const float* __restrict__ x, unsigned short* __restrict__ xT)
{
    __shared__ unsigned short s[64][65];
    const int t = threadIdx.x, lane = t & 63, grp = t >> 6;
    const int hw0 = blockIdx.x * 64, c0 = blockIdx.y * 64, b = blockIdx.z;
#pragma unroll
    for (int j = 0; j < 16; ++j) {
        int cc = grp * 16 + j;
        float v = x[((size_t)(b * 256 + c0 + cc)) * HW + hw0 + lane];
        s[cc][lane] = (unsigned short)f2bf(v);
    }
    __syncthreads();
#pragma unroll
    for (int j = 0; j < 16; ++j) {
        int hw2 = grp * 16 + j;
        xT[((size_t)b * HW + hw0 + hw2) * 256 + c0 + lane] = s[lane][hw2];
    }
}

// ---------------------------------------------------------------------------
// Kernel 2: offset-conv weights -> bf16, padded to 64 rows, K-order
// r = tap*256 + c (matches in-LDS im2col of xT).
// ---------------------------------------------------------------------------
__global__ __launch_bounds__(256) void k_wt2(
    const float* __restrict__ w_off, short* __restrict__ wTb)
{
    int e = blockIdx.x * 256 + threadIdx.x;     // 64*2304 = 147456
    int o = e / 2304, r = e - o * 2304;
    int tap = r >> 8, c = r & 255;
    wTb[e] = (o < 54) ? f2bf(w_off[(o * 256 + c) * 9 + tap]) : (short)0;
}

// ---------------------------------------------------------------------------
// Kernel 3: offset conv as MFMA GEMM. om2[m][n] = sum_r wTb[m][r]*B[n][r],
// M=64 (54 live), N=16384, K=2304, r = tap*256+c. B-tile built in-LDS from
// xT with tap shifts + border zeros (no materialized im2col).
// Tile 64x64x32; 4 waves, wave = full 64m x 16n.
// ---------------------------------------------------------------------------
__global__ __launch_bounds__(256) void k_omgemm(
    const short* __restrict__ wTb, const unsigned short* __restrict__ xT,
    float* __restrict__ om2)
{
    __shared__ short As[64 * 32];
    __shared__ short Bs[64 * 32];
    const int t = threadIdx.x;
    const int wid = __builtin_amdgcn_readfirstlane(t >> 6);
    const int lane = t & 63, quad = lane >> 4, l16 = lane & 15;
    const int n0 = blockIdx.x * 64, b = n0 >> 12;
    const int nr = t >> 2;              // tile row 0..63
    const int ks = (t & 3) * 8;         // bf16 offset within 32-k chunk
    const int px = (n0 + nr) & 4095, h = px >> 6, w = px & 63;
    const unsigned short* xb = xT + (size_t)b * HW * 256;

    f32x4 acc[4];
#pragma unroll
    for (int i = 0; i < 4; ++i) acc[i] = (f32x4){0.f, 0.f, 0.f, 0.f};

    for (int kc = 0; kc < 72; ++kc) {
        const int tap = kc >> 3, c0 = (kc & 7) * 32;
        const int hh = h + tap / 3 - 1, ww = w + tap % 3 - 1;
        uint4 bv = {0u, 0u, 0u, 0u};
        if (hh >= 0 && hh < 64 && ww >= 0 && ww < 64)
            bv = *(const uint4*)(xb + (size_t)(hh * 64 + ww) * 256 + c0 + ks);
        if (kc) __syncthreads();
        glds16(wTb + (size_t)nr * 2304 + kc * 32 + ks, &As[t * 8]);
        *(uint4*)&Bs[t * 8] = bv;
        __syncthreads();
        bf16x8 bf = *(const bf16x8*)&Bs[(wid * 16 + l16) * 32 + quad * 8];
#pragma unroll
        for (int mi = 0; mi < 4; ++mi) {
            bf16x8 af = *(const bf16x8*)&As[(mi * 16 + l16) * 32 + quad * 8];
            acc[mi] = __builtin_amdgcn_mfma_f32_16x16x32_bf16(af, bf, acc[mi], 0, 0, 0);
        }
    }
    const int n = n0 + wid * 16 + l16;
#pragma unroll
    for (int mi = 0; mi < 4; ++mi)
#pragma unroll
        for (int i = 0; i < 4; ++i)
            om2[(size_t)(mi * 16 + quad * 4 + i) * 16384 + n] = acc[mi][i];
}

// ---------------------------------------------------------------------------
// Kernel 4: deformable-GEMM A: a2[o][dg*1152 + tap*128 + c] (bf16).
// ---------------------------------------------------------------------------
__global__ __launch_bounds__(256) void k_wcvt2(
    const float* __restrict__ weight, short* __restrict__ a2)
{
    int e = blockIdx.x * 256 + threadIdx.x;     // 256*2304 = 589824
    int o = e / 2304, r = e - o * 2304;
    int dg = r / 1152, r2 = r - dg * 1152;
    int tap = r2 >> 7, c = r2 & 127;
    a2[e] = f2bf(weight[o * 2304 + (dg * 128 + c) * 9 + tap]);
}

// ---------------------------------------------------------------------------
// Kernel 5: deformable col from NHWC xT. Plan math inlined (wave-uniform).
// Wave = (dg, half); per (px, tap): 4 coalesced 128B corner loads (lane=c),
// one contiguous 128B colT write at r = dg*1152 + tap*128 + half*64 + lane.
// ---------------------------------------------------------------------------
__global__ __launch_bounds__(256) void k_col2(
    const unsigned short* __restrict__ xT, const float* __restrict__ om2,
    const float* __restrict__ b_off, short* __restrict__ colT)
{
    const int t = threadIdx.x;
    const int wid = __builtin_amdgcn_readfirstlane(t >> 6);
    const int lane = t & 63;
    const int dg = wid >> 1, half = wid & 1;
    const int coff = dg * 128 + half * 64 + lane;
    const int n0 = blockIdx.x * 16, b = n0 >> 12;
    const unsigned short* xb = xT + (size_t)b * HW * 256;

    for (int j = 0; j < 16; ++j) {
        const int n = n0 + j;
        const int px = n & 4095, h = px >> 6, w = px & 63;
#pragma unroll
        for (int tap = 0; tap < 9; ++tap) {
            const int cdy = dg * 18 + tap, cdx = cdy + 9, cms = 36 + dg * 9 + tap;
            float dy = om2[(size_t)cdy * 16384 + n] + b_off[cdy];
            float dx = om2[(size_t)cdx * 16384 + n] + b_off[cdx];
            float ms = om2[(size_t)cms * 16384 + n] + b_off[cms];
            ms = 1.f / (1.f + __expf(-ms));
            float py = dy + (float)(h + tap / 3 - 1);
            float qx = dx + (float)(w + tap % 3 - 1);
            float y0f = floorf(py), x0f = floorf(qx);
            float wy1 = py - y0f, wx1 = qx - x0f;
            float wy0 = 1.f - wy1, wx0 = 1.f - wx1;
            int y0 = (int)y0f, x0 = (int)x0f;
            int y1 = y0 + 1, x1 = x0 + 1;
            bool vy0 = (y0 >= 0) & (y0 < 64), vy1 = (y1 >= 0) & (y1 < 64);
            bool vx0 = (x0 >= 0) & (x0 < 64), vx1 = (x1 >= 0) & (x1 < 64);
            int cy0 = min(max(y0, 0), 63), cy1 = min(max(y1, 0), 63);
            int cx0 = min(max(x0, 0), 63), cx1 = min(max(x1, 0), 63);
            float w00 = (vy0 && vx0) ? wy0 * wx0 * ms : 0.f;
            float w01 = (vy0 && vx1) ? wy0 * wx1 * ms : 0.f;
            float w10 = (vy1 && vx0) ? wy1 * wx0 * ms : 0.f;
            float w11 = (vy1 && vx1) ? wy1 * wx1 * ms : 0.f;
            int i0 = cy0 * 64 + cx0, i1 = cy0 * 64 + cx1;
            int i2 = cy1 * 64 + cx0, i3 = cy1 * 64 + cx1;
            float v = w00 * bf2f(xb[(size_t)i0 * 256 + coff])
                    + w01 * bf2f(xb[(size_t)i1 * 256 + coff])
                    + w10 * bf2f(xb[(size_t)i2 * 256 + coff])
                    + w11 * bf2f(xb[(size_t)i3 * 256 + coff]);
            colT[(size_t)n * 2304 + dg * 1152 + tap * 128 + half * 64 + lane] = f2bf(v);
        }
    }
}

// ---------------------------------------------------------------------------
// Kernel 6: deformable GEMM out[m,n] = sum_r a2[m,r]*colT[n,r],
// M=256, N=16384, K=2304. 64x128x32 tile, global_load_lds staging,
// 4 waves (2x2), wave = 32x64 (2x4 MFMA). Grid: m fastest for L3 reuse of B.
// ---------------------------------------------------------------------------
__global__ __launch_bounds__(256) void k_gemm(
    const short* __restrict__ A, const short* __restrict__ Bm,
    const float* __restrict__ bias, float* __restrict__ out)
{
    __shared__ short As[64 * 32];
    __shared__ short Bs[128 * 32];
    const int t = threadIdx.x;
    const int wid = t >> 6, lane = t & 63;
    const int quad = lane >> 4, l16 = lane & 15;
    const int wm = wid >> 1, wn = wid & 1;
    const int bm = blockIdx.x, bn = blockIdx.y;
    const short* Ab = A + (size_t)(bm * 64) * 2304;
    const short* Bb = Bm + (size_t)(bn * 128) * 2304;
    const int nr = t >> 2;              // 0..63
    const int ks = (t & 3) * 8;

    f32x4 acc[2][4];
#pragma unroll
    for (int i = 0; i < 2; ++i)
#pragma unroll
        for (int j = 0; j < 4; ++j) acc[i][j] = (f32x4){0.f, 0.f, 0.f, 0.f};

    for (int kc = 0; kc < 72; ++kc) {
        if (kc) __syncthreads();
        const int k0 = kc * 32 + ks;
        glds16(Ab + (size_t)nr * 2304 + k0, &As[t * 8]);
        glds16(Bb + (size_t)nr * 2304 + k0, &Bs[t * 8]);
        glds16(Bb + (size_t)(nr + 64) * 2304 + k0, &Bs[2048 + t * 8]);
        __syncthreads();
        bf16x8 af[2], bfr[4];
#pragma unroll
        for (int mi = 0; mi < 2; ++mi)
            af[mi] = *(const bf16x8*)&As[(wm * 32 + mi * 16 + l16) * 32 + quad * 8];
#pragma unroll
        for (int ni = 0; ni < 4; ++ni)
            bfr[ni] = *(const bf16x8*)&Bs[(wn * 64 + ni * 16 + l16) * 32 + quad * 8];
#pragma unroll
        for (int mi = 0; mi < 2; ++mi)
#pragma unroll
            for (int ni = 0; ni < 4; ++ni)
                acc[mi][ni] = __builtin_amdgcn_mfma_f32_16x16x32_bf16(
                    af[mi], bfr[ni], acc[mi][ni], 0, 0, 0);
    }

    const int m0 = bm * 64 + wm * 32;
    const int n0 = bn * 128 + wn * 64;
#pragma unroll
    for (int mi = 0; mi < 2; ++mi)
#pragma unroll
        for (int ni = 0; ni < 4; ++ni) {
            int n = n0 + ni * 16 + l16;
            int bidx = n >> 12, hw = n & 4095;
            float* op = out + (size_t)bidx * 256 * 4096 + hw;
#pragma unroll
            for (int i = 0; i < 4; ++i) {
                int m = m0 + mi * 16 + quad * 4 + i;
                op[(size_t)m * 4096] = acc[mi][ni][i] + bias[m];
            }
        }
}

// ---------------------------------------------------------------------------
extern "C" void kernel_launch(void* const* d_in, const int* in_sizes, int n_in,
                              void* d_out, int out_size, void* d_ws, size_t ws_size,
                              hipStream_t stream)
{
    const float* x      = (const float*)d_in[0];
    const float* w_off  = (const float*)d_in[1];
    const float* b_off  = (const float*)d_in[2];
    const float* weight = (const float*)d_in[3];
    const float* bias   = (const float*)d_in[4];
    float* out = (float*)d_out;
    char* ws = (char*)d_ws;

    // ws layout (85,360,640 B total):
    unsigned short* xT  = (unsigned short*)(ws);            //  8,388,608
    short*          a2  = (short*)(ws + 8388608);           //  1,179,648
    short*          wTb = (short*)(ws + 9568256);           //    294,912
    short*          colT= (short*)(ws + 9863168);           // 75,497,472 -> 85,360,640
    // om2 lives in d_out's head (4.19 MB of 16.8 MB); fully consumed by
    // k_col2 before k_gemm overwrites all of d_out. Stream-ordered.
    float*          om2 = (float*)d_out;

    hipLaunchKernelGGL(k_xt, dim3(64, 4, 4), dim3(256), 0, stream, x, xT);
    hipLaunchKernelGGL(k_wt2, dim3(576), dim3(256), 0, stream, w_off, wTb);
    hipLaunchKernelGGL(k_omgemm, dim3(256), dim3(256), 0, stream, wTb, xT, om2);
    hipLaunchKernelGGL(k_wcvt2, dim3(2304), dim3(256), 0, stream, weight, a2);
    hipLaunchKernelGGL(k_col2, dim3(1024), dim3(256), 0, stream, xT, om2, b_off, colT);
    hipLaunchKernelGGL(k_gemm, dim3(4, 128), dim3(256), 0, stream, a2, colT, bias, out);
}

// Round 4
// 199.884 us; speedup vs baseline: 2.6000x; 1.1903x over previous
//
#include <hip/hip_runtime.h>
#include <cstdint>

#define HW 4096

typedef __attribute__((ext_vector_type(8))) short bf16x8;
typedef __attribute__((ext_vector_type(4))) float f32x4;

__device__ __forceinline__ short f2bf(float f) {
    union { float f; uint32_t u; } v; v.f = f;
    uint32_t u = v.u;
    uint32_t r = (u + 0x7FFFu + ((u >> 16) & 1u)) >> 16;
    return (short)(r & 0xFFFFu);
}
__device__ __forceinline__ float bf2f(unsigned short u) {
    union { uint32_t i; float f; } v; v.i = (uint32_t)u << 16; return v.f;
}
// pack two fp32 -> bf16x2 (lo=a, hi=b), round-nearest-even
__device__ __forceinline__ uint32_t packbf(float a, float b) {
    union { float f; uint32_t u; } va, vb; va.f = a; vb.f = b;
    uint32_t ra = va.u + 0x7FFFu + ((va.u >> 16) & 1u);
    uint32_t rb = vb.u + 0x7FFFu + ((vb.u >> 16) & 1u);
    return (ra >> 16) | (rb & 0xFFFF0000u);
}
__device__ __forceinline__ float blo(uint32_t u) { return __uint_as_float(u << 16); }
__device__ __forceinline__ float bhi(uint32_t u) { return __uint_as_float(u & 0xFFFF0000u); }
// async global->LDS, 16B per lane; LDS dest must be wavebase + lane*16
__device__ __forceinline__ void glds16(const void* g, void* l) {
    __builtin_amdgcn_global_load_lds(
        (const __attribute__((address_space(1))) void*)g,
        (__attribute__((address_space(3))) void*)l, 16, 0, 0);
}

// ---------------------------------------------------------------------------
// Kernel 1: transpose x[b][c][hw] (fp32) -> xT[b][hw][c] (bf16).
// ---------------------------------------------------------------------------
__global__ __launch_bounds__(256) void k_xt(
    const float* __restrict__ x, unsigned short* __restrict__ xT)
{
    __shared__ unsigned short s[64][65];
    const int t = threadIdx.x, lane = t & 63, grp = t >> 6;
    const int hw0 = blockIdx.x * 64, c0 = blockIdx.y * 64, b = blockIdx.z;
#pragma unroll
    for (int j = 0; j < 16; ++j) {
        int cc = grp * 16 + j;
        float v = x[((size_t)(b * 256 + c0 + cc)) * HW + hw0 + lane];
        s[cc][lane] = (unsigned short)f2bf(v);
    }
    __syncthreads();
#pragma unroll
    for (int j = 0; j < 16; ++j) {
        int hw2 = grp * 16 + j;
        xT[((size_t)b * HW + hw0 + hw2) * 256 + c0 + lane] = s[lane][hw2];
    }
}

// ---------------------------------------------------------------------------
// Kernel 2: offset-conv weights -> bf16, padded to 64 rows, r = tap*256 + c.
// ---------------------------------------------------------------------------
__global__ __launch_bounds__(256) void k_wt2(
    const float* __restrict__ w_off, short* __restrict__ wTb)
{
    int e = blockIdx.x * 256 + threadIdx.x;     // 147456
    int o = e / 2304, r = e - o * 2304;
    int tap = r >> 8, c = r & 255;
    wTb[e] = (o < 54) ? f2bf(w_off[(o * 256 + c) * 9 + tap]) : (short)0;
}

// ---------------------------------------------------------------------------
// Kernel 3: offset conv as MFMA GEMM; B-tile built in-LDS from xT.
// ---------------------------------------------------------------------------
__global__ __launch_bounds__(256) void k_omgemm(
    const short* __restrict__ wTb, const unsigned short* __restrict__ xT,
    float* __restrict__ om2)
{
    __shared__ short As[64 * 32];
    __shared__ short Bs[64 * 32];
    const int t = threadIdx.x;
    const int wid = __builtin_amdgcn_readfirstlane(t >> 6);
    const int lane = t & 63, quad = lane >> 4, l16 = lane & 15;
    const int n0 = blockIdx.x * 64, b = n0 >> 12;
    const int nr = t >> 2;
    const int ks = (t & 3) * 8;
    const int px = (n0 + nr) & 4095, h = px >> 6, w = px & 63;
    const unsigned short* xb = xT + (size_t)b * HW * 256;

    f32x4 acc[4];
#pragma unroll
    for (int i = 0; i < 4; ++i) acc[i] = (f32x4){0.f, 0.f, 0.f, 0.f};

    for (int kc = 0; kc < 72; ++kc) {
        const int tap = kc >> 3, c0 = (kc & 7) * 32;
        const int hh = h + tap / 3 - 1, ww = w + tap % 3 - 1;
        uint4 bv = {0u, 0u, 0u, 0u};
        if (hh >= 0 && hh < 64 && ww >= 0 && ww < 64)
            bv = *(const uint4*)(xb + (size_t)(hh * 64 + ww) * 256 + c0 + ks);
        if (kc) __syncthreads();
        glds16(wTb + (size_t)nr * 2304 + kc * 32 + ks, &As[t * 8]);
        *(uint4*)&Bs[t * 8] = bv;
        __syncthreads();
        bf16x8 bf = *(const bf16x8*)&Bs[(wid * 16 + l16) * 32 + quad * 8];
#pragma unroll
        for (int mi = 0; mi < 4; ++mi) {
            bf16x8 af = *(const bf16x8*)&As[(mi * 16 + l16) * 32 + quad * 8];
            acc[mi] = __builtin_amdgcn_mfma_f32_16x16x32_bf16(af, bf, acc[mi], 0, 0, 0);
        }
    }
    const int n = n0 + wid * 16 + l16;
#pragma unroll
    for (int mi = 0; mi < 4; ++mi)
#pragma unroll
        for (int i = 0; i < 4; ++i)
            om2[(size_t)(mi * 16 + quad * 4 + i) * 16384 + n] = acc[mi][i];
}

// ---------------------------------------------------------------------------
// Kernel 4: deformable-GEMM A: a2[o][dg*1152 + tap*128 + c] (bf16).
// ---------------------------------------------------------------------------
__global__ __launch_bounds__(256) void k_wcvt2(
    const float* __restrict__ weight, short* __restrict__ a2)
{
    int e = blockIdx.x * 256 + threadIdx.x;     // 589824
    int o = e / 2304, r = e - o * 2304;
    int dg = r / 1152, r2 = r - dg * 1152;
    int tap = r2 >> 7, c = r2 & 127;
    a2[e] = f2bf(weight[o * 2304 + (dg * 128 + c) * 9 + tap]);
}

// ---------------------------------------------------------------------------
// Kernel 5: sampling plan. Per e = s*16384+n (s = dg*9+tap, n = b*4096+hw):
// 4 bilinear weights (validity & sigmoid(mask) folded) + 4 gather byte-offsets
// (premultiplied by 512 = bytes per pixel row of xT).
// ---------------------------------------------------------------------------
__global__ __launch_bounds__(256) void k_plan(
    const float* __restrict__ om2, const float* __restrict__ b_off,
    float4* __restrict__ planw, int4* __restrict__ plani)
{
    int e = blockIdx.x * 256 + threadIdx.x;      // 18*16384 = 294912
    int n = e & 16383, s = e >> 14;
    int dg = s >= 9 ? 1 : 0, tap = s - dg * 9;
    int h = (n >> 6) & 63, w = n & 63;
    int cdy = dg * 18 + tap, cdx = cdy + 9, cms = 36 + dg * 9 + tap;
    float dy = om2[(size_t)cdy * 16384 + n] + b_off[cdy];
    float dx = om2[(size_t)cdx * 16384 + n] + b_off[cdx];
    float ms = om2[(size_t)cms * 16384 + n] + b_off[cms];
    ms = 1.f / (1.f + __expf(-ms));
    float py = dy + (float)(h + tap / 3 - 1);
    float qx = dx + (float)(w + tap % 3 - 1);
    float y0f = floorf(py), x0f = floorf(qx);
    float wy1 = py - y0f, wx1 = qx - x0f;
    float wy0 = 1.f - wy1, wx0 = 1.f - wx1;
    int y0 = (int)y0f, x0 = (int)x0f;
    int y1 = y0 + 1, x1 = x0 + 1;
    bool vy0 = (y0 >= 0) & (y0 < 64), vy1 = (y1 >= 0) & (y1 < 64);
    bool vx0 = (x0 >= 0) & (x0 < 64), vx1 = (x1 >= 0) & (x1 < 64);
    int cy0 = min(max(y0, 0), 63), cy1 = min(max(y1, 0), 63);
    int cx0 = min(max(x0, 0), 63), cx1 = min(max(x1, 0), 63);
    float4 wv;
    wv.x = (vy0 && vx0) ? wy0 * wx0 * ms : 0.f;
    wv.y = (vy0 && vx1) ? wy0 * wx1 * ms : 0.f;
    wv.z = (vy1 && vx0) ? wy1 * wx0 * ms : 0.f;
    wv.w = (vy1 && vx1) ? wy1 * wx1 * ms : 0.f;
    int4 iv = make_int4((cy0 * 64 + cx0) << 9, (cy0 * 64 + cx1) << 9,
                        (cy1 * 64 + cx0) << 9, (cy1 * 64 + cx1) << 9);
    planw[e] = wv;
    plani[e] = iv;
}

// ---------------------------------------------------------------------------
// Kernel 6: deformable col. One wave covers ALL 256 channels (4 ch/lane,
// uint2 loads): plan cost paid once per (n,tap). Lane l: ch 4l..4l+3,
// dg = l>>5 (plan loads broadcast per half-wave). Corner loads: 2 coalesced
// 256B segments per instruction; colT store: 2 contiguous 256B segments.
// ---------------------------------------------------------------------------
__global__ __launch_bounds__(256) void k_col2(
    const unsigned short* __restrict__ xT, const float4* __restrict__ planw,
    const int4* __restrict__ plani, short* __restrict__ colT)
{
    const int t = threadIdx.x;
    const int wid = __builtin_amdgcn_readfirstlane(t >> 6);
    const int lane = t & 63;
    const int dgl = lane >> 5, c32 = lane & 31;
    const int n0 = blockIdx.x * 16, b = n0 >> 12;
    const char* xbb = (const char*)xT + (size_t)b * HW * 512;
    const int off8 = lane * 8;

    for (int jj = 0; jj < 4; ++jj) {
        const int n = n0 + jj * 4 + wid;
        char* crow = (char*)colT + (size_t)n * 4608 + (size_t)dgl * 2304 + c32 * 8;
#pragma unroll
        for (int tap = 0; tap < 9; ++tap) {
            const int s = dgl * 9 + tap;
            float4 w4 = planw[(size_t)s * 16384 + n];
            int4 i4 = plani[(size_t)s * 16384 + n];
            uint2 d0 = *(const uint2*)(xbb + i4.x + off8);
            uint2 d1 = *(const uint2*)(xbb + i4.y + off8);
            uint2 d2 = *(const uint2*)(xbb + i4.z + off8);
            uint2 d3 = *(const uint2*)(xbb + i4.w + off8);
            float a0 = w4.x * blo(d0.x) + w4.y * blo(d1.x) + w4.z * blo(d2.x) + w4.w * blo(d3.x);
            float a1 = w4.x * bhi(d0.x) + w4.y * bhi(d1.x) + w4.z * bhi(d2.x) + w4.w * bhi(d3.x);
            float a2 = w4.x * blo(d0.y) + w4.y * blo(d1.y) + w4.z * blo(d2.y) + w4.w * blo(d3.y);
            float a3 = w4.x * bhi(d0.y) + w4.y * bhi(d1.y) + w4.z * bhi(d2.y) + w4.w * bhi(d3.y);
            uint2 o;
            o.x = packbf(a0, a1);
            o.y = packbf(a2, a3);
            *(uint2*)(crow + tap * 256) = o;
        }
    }
}

// ---------------------------------------------------------------------------
// Kernel 7: deformable GEMM out[m,n] = sum_r a2[m,r]*colT[n,r],
// M=256, N=16384, K=2304. 64x128x32 tile, global_load_lds staging.
// ---------------------------------------------------------------------------
__global__ __launch_bounds__(256) void k_gemm(
    const short* __restrict__ A, const short* __restrict__ Bm,
    const float* __restrict__ bias, float* __restrict__ out)
{
    __shared__ short As[64 * 32];
    __shared__ short Bs[128 * 32];
    const int t = threadIdx.x;
    const int wid = t >> 6, lane = t & 63;
    const int quad = lane >> 4, l16 = lane & 15;
    const int wm = wid >> 1, wn = wid & 1;
    const int bm = blockIdx.x, bn = blockIdx.y;
    const short* Ab = A + (size_t)(bm * 64) * 2304;
    const short* Bb = Bm + (size_t)(bn * 128) * 2304;
    const int nr = t >> 2;
    const int ks = (t & 3) * 8;

    f32x4 acc[2][4];
#pragma unroll
    for (int i = 0; i < 2; ++i)
#pragma unroll
        for (int j = 0; j < 4; ++j) acc[i][j] = (f32x4){0.f, 0.f, 0.f, 0.f};

    for (int kc = 0; kc < 72; ++kc) {
        if (kc) __syncthreads();
        const int k0 = kc * 32 + ks;
        glds16(Ab + (size_t)nr * 2304 + k0, &As[t * 8]);
        glds16(Bb + (size_t)nr * 2304 + k0, &Bs[t * 8]);
        glds16(Bb + (size_t)(nr + 64) * 2304 + k0, &Bs[2048 + t * 8]);
        __syncthreads();
        bf16x8 af[2], bfr[4];
#pragma unroll
        for (int mi = 0; mi < 2; ++mi)
            af[mi] = *(const bf16x8*)&As[(wm * 32 + mi * 16 + l16) * 32 + quad * 8];
#pragma unroll
        for (int ni = 0; ni < 4; ++ni)
            bfr[ni] = *(const bf16x8*)&Bs[(wn * 64 + ni * 16 + l16) * 32 + quad * 8];
#pragma unroll
        for (int mi = 0; mi < 2; ++mi)
#pragma unroll
            for (int ni = 0; ni < 4; ++ni)
                acc[mi][ni] = __builtin_amdgcn_mfma_f32_16x16x32_bf16(
                    af[mi], bfr[ni], acc[mi][ni], 0, 0, 0);
    }

    const int m0 = bm * 64 + wm * 32;
    const int n0 = bn * 128 + wn * 64;
#pragma unroll
    for (int mi = 0; mi < 2; ++mi)
#pragma unroll
        for (int ni = 0; ni < 4; ++ni) {
            int n = n0 + ni * 16 + l16;
            int bidx = n >> 12, hw = n & 4095;
            float* op = out + (size_t)bidx * 256 * 4096 + hw;
#pragma unroll
            for (int i = 0; i < 4; ++i) {
                int m = m0 + mi * 16 + quad * 4 + i;
                op[(size_t)m * 4096] = acc[mi][ni][i] + bias[m];
            }
        }
}

// ---------------------------------------------------------------------------
extern "C" void kernel_launch(void* const* d_in, const int* in_sizes, int n_in,
                              void* d_out, int out_size, void* d_ws, size_t ws_size,
                              hipStream_t stream)
{
    const float* x      = (const float*)d_in[0];
    const float* w_off  = (const float*)d_in[1];
    const float* b_off  = (const float*)d_in[2];
    const float* weight = (const float*)d_in[3];
    const float* bias   = (const float*)d_in[4];
    float* out = (float*)d_out;
    char* ws = (char*)d_ws;

    // ws layout (85,360,640 B total):
    unsigned short* xT  = (unsigned short*)(ws);            //  8,388,608
    short*          a2  = (short*)(ws + 8388608);           //  1,179,648
    short*          wTb = (short*)(ws + 9568256);           //    294,912
    short*          colT= (short*)(ws + 9863168);           // 75,497,472 -> 85,360,640
    // om2 + plan buffers live in d_out (16.78 MB), all dead before k_gemm
    // overwrites every byte of d_out. Stream-ordered.
    float*          om2   = (float*)d_out;                  //  4,194,304 (64 rows x 16384)
    float4*         planw = (float4*)((char*)d_out + 4194304);   // 4,718,592
    int4*           plani = (int4*)((char*)d_out + 8912896);     // 4,718,592 -> 13,631,488

    hipLaunchKernelGGL(k_xt, dim3(64, 4, 4), dim3(256), 0, stream, x, xT);
    hipLaunchKernelGGL(k_wt2, dim3(576), dim3(256), 0, stream, w_off, wTb);
    hipLaunchKernelGGL(k_omgemm, dim3(256), dim3(256), 0, stream, wTb, xT, om2);
    hipLaunchKernelGGL(k_wcvt2, dim3(2304), dim3(256), 0, stream, weight, a2);
    hipLaunchKernelGGL(k_plan, dim3(1152), dim3(256), 0, stream, om2, b_off, planw, plani);
    hipLaunchKernelGGL(k_col2, dim3(1024), dim3(256), 0, stream, xT, planw, plani, colT);
    hipLaunchKernelGGL(k_gemm, dim3(4, 128), dim3(256), 0, stream, a2, colT, bias, out);
}